// Round 3
// baseline (341.174 us; speedup 1.0000x reference)
//
#include <hip/hip_runtime.h>
#include <stdint.h>

#define M_DIM 8192
#define N_DIM 4096
#define K_DIM 4096
#define NBLK  (K_DIM / 32)

typedef __attribute__((ext_vector_type(4))) float          f32x4;
typedef __attribute__((ext_vector_type(8))) short          bf16x8;
typedef __attribute__((ext_vector_type(4))) int            i32x4;
typedef __attribute__((ext_vector_type(8))) unsigned short u16x8;
typedef __attribute__((address_space(3))) unsigned short   lds_us;

// round-to-nearest-even fp32 -> bf16 bits (finite values only)
__device__ __forceinline__ unsigned short f2bf(float f) {
  unsigned u = __builtin_bit_cast(unsigned, f);
  u += 0x7fffu + ((u >> 16) & 1u);
  return (unsigned short)(u >> 16);
}

__device__ __forceinline__ void stage16(const unsigned short* g, lds_us* l) {
  __builtin_amdgcn_global_load_lds(
      (const __attribute__((address_space(1))) void*)g,
      (__attribute__((address_space(3))) void*)l, 16, 0, 0);
}

// inline-asm ds_read_b128 with immediate byte offset; volatile order is the
// contract the counted lgkmcnt waits rely on.
template <int OFF>
__device__ __forceinline__ bf16x8 dsr(lds_us* addr) {
  bf16x8 d;
  asm volatile("ds_read_b128 %0, %1 offset:%2" : "=v"(d) : "v"(addr), "n"(OFF));
  return d;
}

// ---------------- dequant: wq int32 [N,K], scales [N,K/32] -> wb bf16-bits [N,K]
__global__ void MXFP4_dequant_kernel(const int* __restrict__ wq,
                                     const float* __restrict__ scales,
                                     unsigned short* __restrict__ wb) {
  int t = blockIdx.x * 256 + threadIdx.x;
  long e = (long)t * 8;
  int o = t >> 9;
  int k = (t & 511) << 3;
  float s = scales[o * NBLK + (k >> 5)] * (1.0f / 7.0f);
  i32x4 q0 = *(const i32x4*)(wq + e);
  i32x4 q1 = *(const i32x4*)(wq + e + 4);
  u16x8 r;
#pragma unroll
  for (int j = 0; j < 4; ++j) r[j]     = f2bf((float)q0[j] * s);
#pragma unroll
  for (int j = 0; j < 4; ++j) r[4 + j] = f2bf((float)q1[j] * s);
  *(u16x8*)(wb + e) = r;
}

// ---------------- x fp32 -> bf16-bits
__global__ void MXFP4_cvt_kernel(const float* __restrict__ x,
                                 unsigned short* __restrict__ xb) {
  long t = (long)blockIdx.x * 256 + threadIdx.x;
  long e = t * 8;
  f32x4 v0 = *(const f32x4*)(x + e);
  f32x4 v1 = *(const f32x4*)(x + e + 4);
  u16x8 r;
#pragma unroll
  for (int j = 0; j < 4; ++j) r[j]     = f2bf(v0[j]);
#pragma unroll
  for (int j = 0; j < 4; ++j) r[4 + j] = f2bf(v1[j]);
  *(u16x8*)(xb + e) = r;
}

// ---------------- GEMM: A [M,K] bf16, B [N,K] bf16 (B^T), C [M,N] f32 + bias
// 256x256 tile, BK=64, 8 waves (2Mx4N), 8-phase schedule, counted vmcnt(4),
// fragment-ordered LDS subtiles (zero bank conflict), software-pipelined
// ds_reads with counted lgkmcnt (each read batch overlaps an MFMA cluster):
//   ph4(g-1): issue aLo,bLo(g)   || MF Q11(g-1)
//   ph1(g):   issue aHi(g), wait lgkm(8)  -> MF Q00 || aHi completing
//   ph2(g):   issue bHi(g), wait lgkm(4)  -> MF Q10 || bHi completing
//   ph3(g):   wait lgkm(0)                -> MF Q01
//   ph4(g):   vmcnt(4), issue next aLo,bLo -> MF Q11
//
// LDS element map: A buf b at b*16384; B buf b at 32768+b*16384; dummy 65536.
// Subtile (16 rows x 32 K) = 1024B in MFMA lane order: lane l <-> (row l&15,
// k-chunk (l>>4)*8), 16B per lane.

#define BAR() __builtin_amdgcn_s_barrier()
#define WAIT_LGKM(N_) do { asm volatile("s_waitcnt lgkmcnt(%0)" :: "n"(N_) : "memory"); \
                           __builtin_amdgcn_sched_barrier(0); } while (0)

#define ST_A(t_, h_, BUFA_, valid_) do { \
  if (valid_) { \
    const unsigned short* s_ = srcA + (size_t)(h_) * 128 * K_DIM + (t_) * 64; \
    lds_us* d_ = lp + (BUFA_) * 16384 + ((h_) * 8 + wv) * 1024; \
    stage16(s_, d_); stage16(s_ + 32, d_ + 512); \
  } else { stage16(srcA, lp + 65536); stage16(srcA + 32, lp + 65536 + 512); } \
} while (0)

#define ST_B(t_, h_, BUFB_, valid_) do { \
  if (valid_) { \
    const unsigned short* s_ = srcB + (size_t)(h_) * 128 * K_DIM + (t_) * 64; \
    lds_us* d_ = lp + 32768 + (BUFB_) * 16384 + ((h_) * 8 + wv) * 1024; \
    stage16(s_, d_); stage16(s_ + 32, d_ + 512); \
  } else { stage16(srcB, lp + 65536); stage16(srcB + 32, lp + 65536 + 512); } \
} while (0)

#define MF(MB_, NB_, AF_, BF_) do { \
  _Pragma("unroll") \
  for (int kk_ = 0; kk_ < 2; ++kk_) \
    _Pragma("unroll") \
    for (int mm_ = 0; mm_ < 4; ++mm_) \
      _Pragma("unroll") \
      for (int nn_ = 0; nn_ < 2; ++nn_) \
        acc[(MB_) + mm_][(NB_) + nn_] = __builtin_amdgcn_mfma_f32_16x16x32_bf16( \
            AF_[mm_][kk_], BF_[nn_][kk_], acc[(MB_) + mm_][(NB_) + nn_], 0, 0, 0); \
} while (0)

#define RD_ALO_BLO(dsA_, dsB_) do { \
  aLo[0][0] = dsr<0>(dsA_);      aLo[0][1] = dsr<1024>(dsA_); \
  aLo[1][0] = dsr<2048>(dsA_);   aLo[1][1] = dsr<3072>(dsA_); \
  aLo[2][0] = dsr<4096>(dsA_);   aLo[2][1] = dsr<5120>(dsA_); \
  aLo[3][0] = dsr<6144>(dsA_);   aLo[3][1] = dsr<7168>(dsA_); \
  bLo[0][0] = dsr<0>(dsB_);      bLo[0][1] = dsr<1024>(dsB_); \
  bLo[1][0] = dsr<2048>(dsB_);   bLo[1][1] = dsr<3072>(dsB_); \
} while (0)

// One 4-phase group computing K-tile g from buffer BUF_ (= g&1).
// On entry: aLo,bLo of tile g already ISSUED (12 outstanding lgkm ops).
// Stages: ph1/ph2 -> B(tB_) into BUF_^1; ph3/ph4 -> A(tA_) into BUF_.
// ph4: vmcnt(4) publishes tile g+1; if RDN_, issue aLo,bLo of g+1 from BUF_^1.
#define GROUP(BUF_, tB_, tA_, vB_, vA_, RDN_) do { \
  lds_us* dsA_ = lp + (BUF_) * 16384 + wm * 8192 + lane * 8; \
  lds_us* dsB_ = lp + 32768 + (BUF_) * 16384 + wn * 4096 + lane * 8; \
  lds_us* dsA2_ = lp + ((BUF_) ^ 1) * 16384 + wm * 8192 + lane * 8; \
  lds_us* dsB2_ = lp + 32768 + ((BUF_) ^ 1) * 16384 + wn * 4096 + lane * 8; \
  /* ---- phase 1: Q00 (m0-3, n0-1) ---- */ \
  aHi[0][0] = dsr<8192>(dsA_);   aHi[0][1] = dsr<9216>(dsA_); \
  aHi[1][0] = dsr<10240>(dsA_);  aHi[1][1] = dsr<11264>(dsA_); \
  aHi[2][0] = dsr<12288>(dsA_);  aHi[2][1] = dsr<13312>(dsA_); \
  aHi[3][0] = dsr<14336>(dsA_);  aHi[3][1] = dsr<15360>(dsA_); \
  ST_B(tB_, 0, (BUF_) ^ 1, vB_); \
  BAR(); WAIT_LGKM(8); /* drain aLo,bLo; aHi stays in flight */ \
  __builtin_amdgcn_s_setprio(1); \
  MF(0, 0, aLo, bLo); \
  __builtin_amdgcn_s_setprio(0); \
  BAR(); \
  /* ---- phase 2: Q10 (m4-7, n0-1) ---- */ \
  bHi[0][0] = dsr<4096>(dsB_);   bHi[0][1] = dsr<5120>(dsB_); \
  bHi[1][0] = dsr<6144>(dsB_);   bHi[1][1] = dsr<7168>(dsB_); \
  ST_B(tB_, 1, (BUF_) ^ 1, vB_); \
  BAR(); WAIT_LGKM(4); /* drain aHi; bHi stays in flight */ \
  __builtin_amdgcn_s_setprio(1); \
  MF(4, 0, aHi, bLo); \
  __builtin_amdgcn_s_setprio(0); \
  BAR(); \
  /* ---- phase 3: Q01 (m0-3, n2-3) ---- */ \
  ST_A(tA_, 0, (BUF_), vA_); \
  BAR(); WAIT_LGKM(0); /* drain bHi */ \
  __builtin_amdgcn_s_setprio(1); \
  MF(0, 2, aLo, bHi); \
  __builtin_amdgcn_s_setprio(0); \
  BAR(); \
  /* ---- phase 4: Q11 (m4-7, n2-3) ---- */ \
  ST_A(tA_, 1, (BUF_), vA_); \
  asm volatile("s_waitcnt vmcnt(4)" ::: "memory"); \
  BAR(); \
  if (RDN_) { RD_ALO_BLO(dsA2_, dsB2_); } \
  __builtin_amdgcn_s_setprio(1); \
  MF(4, 2, aHi, bHi); \
  __builtin_amdgcn_s_setprio(0); \
  BAR(); \
} while (0)

__global__ __launch_bounds__(512, 2) void MXFP4_gemm_kernel(
    const unsigned short* __restrict__ A,
    const unsigned short* __restrict__ B,
    const float* __restrict__ bias,
    float* __restrict__ C) {
  __shared__ unsigned short LDS[66560];  // 130 KB
  lds_us* lp = (lds_us*)LDS;

  const int tid  = threadIdx.x;
  const int lane = tid & 63;
  const int wv   = tid >> 6;   // wave 0..7
  const int wm   = wv >> 2;    // 0..1  (M half)
  const int wn   = wv & 3;     // 0..3  (N quarter)

  // XCD-aware bijective swizzle (512 blocks % 8 == 0), tn-major within XCD
  const int bid = blockIdx.x;
  const int sw  = (bid & 7) * 64 + (bid >> 3);
  const int tn  = sw >> 5;     // 0..15
  const int tm  = sw & 31;     // 0..31
  const int brow = tm * 256;
  const int bcol = tn * 256;

  // per-thread global staging bases (fragment-order permuted source)
  const unsigned short* srcA =
      A + (size_t)(brow + wv * 16 + (lane & 15)) * K_DIM + ((lane >> 4) * 8);
  const unsigned short* srcB =
      B + (size_t)(bcol + wv * 16 + (lane & 15)) * K_DIM + ((lane >> 4) * 8);

  f32x4 acc[8][4] = {};
  bf16x8 aLo[4][2], aHi[4][2], bLo[2][2], bHi[2][2];

  // ---- prologue: tile 0 (A lo/hi, B lo/hi) + tile 1 A halves ----
  ST_A(0, 0, 0, true); ST_A(0, 1, 0, true);
  ST_B(0, 0, 0, true); ST_B(0, 1, 0, true);
  ST_A(1, 0, 1, true); ST_A(1, 1, 1, true);
  asm volatile("s_waitcnt vmcnt(4)" ::: "memory");  // tile 0 landed; A(1) in flight
  BAR();
  {  // issue aLo,bLo of tile 0 (buffer 0) — drained at first GROUP's ph1
    lds_us* dsA0 = lp + wm * 8192 + lane * 8;
    lds_us* dsB0 = lp + 32768 + wn * 4096 + lane * 8;
    RD_ALO_BLO(dsA0, dsB0);
  }

  // ---- main loop: 31 iters x 2 K-tiles ----
  for (int it = 0; it < 31; ++it) {
    const int g0 = 2 * it;
    GROUP(0, g0 + 1, g0 + 2, true, true, true);
    GROUP(1, g0 + 2, g0 + 3, true, true, true);
  }
  // ---- tail groups 62, 63 (dummy stages keep vmcnt accounting uniform) ----
  GROUP(0, 63, 64, true, false, true);
  GROUP(1, 64, 65, false, false, false);

  // ---- epilogue: C = acc + bias;  frag: col=lane&15, row=(lane>>4)*4+j ----
  const int rb = brow + wm * 128 + (lane >> 4) * 4;
  const int cb = bcol + wn * 64 + (lane & 15);
#pragma unroll
  for (int n = 0; n < 4; ++n) {
    const int col = cb + n * 16;
    const float bv = bias[col];
#pragma unroll
    for (int m = 0; m < 8; ++m) {
      const int row = rb + m * 16;
#pragma unroll
      for (int j = 0; j < 4; ++j)
        C[(size_t)(row + j) * N_DIM + col] = acc[m][n][j] + bv;
    }
  }
}

extern "C" void kernel_launch(void* const* d_in, const int* in_sizes, int n_in,
                              void* d_out, int out_size, void* d_ws, size_t ws_size,
                              hipStream_t stream) {
  const float* x      = (const float*)d_in[0];
  const int*   wq     = (const int*)d_in[1];
  const float* scales = (const float*)d_in[2];
  const float* bias   = (const float*)d_in[3];
  float*       out    = (float*)d_out;

  unsigned short* wb = (unsigned short*)d_ws;                    // 33.5 MB
  unsigned short* xb = wb + (size_t)N_DIM * K_DIM;               // 67 MB

  MXFP4_dequant_kernel<<<(N_DIM * (long)K_DIM / 8) / 256, 256, 0, stream>>>(wq, scales, wb);
  MXFP4_cvt_kernel<<<(M_DIM * (long)K_DIM / 8) / 256, 256, 0, stream>>>(x, xb);

  MXFP4_gemm_kernel<<<512, 512, 0, stream>>>(xb, wb, bias, out);
}

// Round 4
// 303.708 us; speedup vs baseline: 1.1234x; 1.1234x over previous
//
#include <hip/hip_runtime.h>
#include <stdint.h>

#define M_DIM 8192
#define N_DIM 4096
#define K_DIM 4096
#define NBLK  (K_DIM / 32)

typedef __attribute__((ext_vector_type(4))) float          f32x4;
typedef __attribute__((ext_vector_type(8))) short          bf16x8;
typedef __attribute__((ext_vector_type(4))) int            i32x4;
typedef __attribute__((ext_vector_type(8))) unsigned short u16x8;
typedef __attribute__((address_space(3))) unsigned short   lds_us;

// round-to-nearest-even fp32 -> bf16 bits (finite values only)
__device__ __forceinline__ unsigned short f2bf(float f) {
  unsigned u = __builtin_bit_cast(unsigned, f);
  u += 0x7fffu + ((u >> 16) & 1u);
  return (unsigned short)(u >> 16);
}

__device__ __forceinline__ void stage16(const unsigned short* g, lds_us* l) {
  __builtin_amdgcn_global_load_lds(
      (const __attribute__((address_space(1))) void*)g,
      (__attribute__((address_space(3))) void*)l, 16, 0, 0);
}

// inline-asm ds_read_b128 with immediate byte offset
template <int OFF>
__device__ __forceinline__ bf16x8 dsr(lds_us* addr) {
  bf16x8 d;
  asm volatile("ds_read_b128 %0, %1 offset:%2" : "=v"(d) : "v"(addr), "n"(OFF));
  return d;
}

// ============ BLOCKED GLOBAL LAYOUT for xb / wb ============
// Element (row, k) lives at granule G = ((g*NH + H)*16 + R*2 + Kt)*64 + c*16 + r
// where g=k/64, Kt=(k%64)/32, c=(k%32)/8, e=k%8, H=row/128, R=(row%128)/16,
// r=row%16; flat elem = G*8 + e.  One granule = 8 elems = 16 B (one MFMA frag
// slice).  A (row-half, K-tile) pair occupies a contiguous 16-KB block, and
// within a 1-KB subtile, granule slot index == MFMA lane — so GEMM staging is
// an identity copy (1 KB contiguous per wave) and ds_reads are conflict-free.

// ---------------- dequant: wq int32 [N,K] row-major -> wb blocked bf16
__global__ void MXFP4_dequant_kernel(const int* __restrict__ wq,
                                     const float* __restrict__ scales,
                                     unsigned short* __restrict__ wb) {
  size_t t = (size_t)blockIdx.x * 256 + threadIdx.x;   // granule id, < 2^21
  int slot = (int)(t & 63);
  int r = slot & 15, c = slot >> 4;
  int sub = (int)(t >> 6) & 15;
  int R = sub >> 1, Kt = sub & 1;
  int H = (int)(t >> 10) & 31;
  int g = (int)(t >> 15);
  size_t row = (size_t)H * 128 + R * 16 + r;
  size_t k   = (size_t)g * 64 + Kt * 32 + c * 8;
  float s = scales[row * NBLK + (g * 2 + Kt)] * (1.0f / 7.0f);
  const int* src = wq + row * K_DIM + k;
  i32x4 q0 = *(const i32x4*)src;
  i32x4 q1 = *(const i32x4*)(src + 4);
  u16x8 out;
#pragma unroll
  for (int j = 0; j < 4; ++j) out[j]     = f2bf((float)q0[j] * s);
#pragma unroll
  for (int j = 0; j < 4; ++j) out[4 + j] = f2bf((float)q1[j] * s);
  *(u16x8*)(wb + t * 8) = out;
}

// ---------------- x fp32 [M,K] row-major -> xb blocked bf16
__global__ void MXFP4_cvt_kernel(const float* __restrict__ x,
                                 unsigned short* __restrict__ xb) {
  size_t t = (size_t)blockIdx.x * 256 + threadIdx.x;   // granule id, < 2^22
  int slot = (int)(t & 63);
  int r = slot & 15, c = slot >> 4;
  int sub = (int)(t >> 6) & 15;
  int R = sub >> 1, Kt = sub & 1;
  int H = (int)(t >> 10) & 63;
  int g = (int)(t >> 16);
  size_t row = (size_t)H * 128 + R * 16 + r;
  size_t k   = (size_t)g * 64 + Kt * 32 + c * 8;
  const float* src = x + row * K_DIM + k;
  f32x4 v0 = *(const f32x4*)src;
  f32x4 v1 = *(const f32x4*)(src + 4);
  u16x8 out;
#pragma unroll
  for (int j = 0; j < 4; ++j) out[j]     = f2bf(v0[j]);
#pragma unroll
  for (int j = 0; j < 4; ++j) out[4 + j] = f2bf(v1[j]);
  *(u16x8*)(xb + t * 8) = out;
}

// ---------------- GEMM: A,B pre-blocked bf16, C [M,N] f32 + bias
// 256x256 tile, BK=64, 8 waves (2Mx4N), 8-phase schedule, counted vmcnt(4),
// identity-copy staging (1 KB contiguous per wave), zero bank conflicts.
// LDS elems: A buf b at b*16384; B buf b at 32768+b*16384; dummy at 65536.

#define BAR() __builtin_amdgcn_s_barrier()
#define WAIT_LGKM0() do { asm volatile("s_waitcnt lgkmcnt(0)" ::: "memory"); \
                          __builtin_amdgcn_sched_barrier(0); } while (0)

#define ST_A(t_, h_, BUFA_, valid_) do { \
  if (valid_) { \
    const unsigned short* s_ = Abase + ((size_t)(t_) * 64 + (h_)) * 8192 + tid8; \
    lds_us* d_ = lp + (BUFA_) * 16384 + (h_) * 8192 + tid8; \
    stage16(s_, d_); stage16(s_ + 4096, d_ + 4096); \
  } else { stage16(Abase + tid8, lp + 65536); \
           stage16(Abase + tid8 + 4096, lp + 65536 + 512); } \
} while (0)

#define ST_B(t_, h_, BUFB_, valid_) do { \
  if (valid_) { \
    const unsigned short* s_ = Bbase + ((size_t)(t_) * 32 + (h_)) * 8192 + tid8; \
    lds_us* d_ = lp + 32768 + (BUFB_) * 16384 + (h_) * 8192 + tid8; \
    stage16(s_, d_); stage16(s_ + 4096, d_ + 4096); \
  } else { stage16(Bbase + tid8, lp + 65536); \
           stage16(Bbase + tid8 + 4096, lp + 65536 + 512); } \
} while (0)

#define MF(MB_, NB_, AF_, BF_) do { \
  _Pragma("unroll") \
  for (int kk_ = 0; kk_ < 2; ++kk_) \
    _Pragma("unroll") \
    for (int mm_ = 0; mm_ < 4; ++mm_) \
      _Pragma("unroll") \
      for (int nn_ = 0; nn_ < 2; ++nn_) \
        acc[(MB_) + mm_][(NB_) + nn_] = __builtin_amdgcn_mfma_f32_16x16x32_bf16( \
            AF_[mm_][kk_], BF_[nn_][kk_], acc[(MB_) + mm_][(NB_) + nn_], 0, 0, 0); \
} while (0)

// One 4-phase group computing K-tile g from buffer BUF_ (= g&1).
// Stages: ph1/ph2 -> B(tB_) halves into BUF_^1; ph3/ph4 -> A(tA_) into BUF_
// (A-region reads complete at ph2's lgkm drain). vmcnt(4) at ph4 publishes
// tile g+1 (A+B), leaving A(g+2)'s 4 loads in flight across the barrier.
#define GROUP(BUF_, tB_, tA_, vB_, vA_) do { \
  lds_us* dsA_ = lp + (BUF_) * 16384 + wm * 8192 + lane * 8; \
  lds_us* dsB_ = lp + 32768 + (BUF_) * 16384 + wn * 4096 + lane * 8; \
  /* ---- phase 1: Q00 (m0-3, n0-1) ---- */ \
  aLo[0][0] = dsr<0>(dsA_);      aLo[0][1] = dsr<1024>(dsA_); \
  aLo[1][0] = dsr<2048>(dsA_);   aLo[1][1] = dsr<3072>(dsA_); \
  aLo[2][0] = dsr<4096>(dsA_);   aLo[2][1] = dsr<5120>(dsA_); \
  aLo[3][0] = dsr<6144>(dsA_);   aLo[3][1] = dsr<7168>(dsA_); \
  bLo[0][0] = dsr<0>(dsB_);      bLo[0][1] = dsr<1024>(dsB_); \
  bLo[1][0] = dsr<2048>(dsB_);   bLo[1][1] = dsr<3072>(dsB_); \
  ST_B(tB_, 0, (BUF_) ^ 1, vB_); \
  BAR(); WAIT_LGKM0(); \
  __builtin_amdgcn_s_setprio(1); \
  MF(0, 0, aLo, bLo); \
  __builtin_amdgcn_s_setprio(0); \
  BAR(); \
  /* ---- phase 2: Q10 (m4-7, n0-1) ---- */ \
  aHi[0][0] = dsr<8192>(dsA_);   aHi[0][1] = dsr<9216>(dsA_); \
  aHi[1][0] = dsr<10240>(dsA_);  aHi[1][1] = dsr<11264>(dsA_); \
  aHi[2][0] = dsr<12288>(dsA_);  aHi[2][1] = dsr<13312>(dsA_); \
  aHi[3][0] = dsr<14336>(dsA_);  aHi[3][1] = dsr<15360>(dsA_); \
  ST_B(tB_, 1, (BUF_) ^ 1, vB_); \
  BAR(); WAIT_LGKM0(); \
  __builtin_amdgcn_s_setprio(1); \
  MF(4, 0, aHi, bLo); \
  __builtin_amdgcn_s_setprio(0); \
  BAR(); \
  /* ---- phase 3: Q01 (m0-3, n2-3) ---- */ \
  bHi[0][0] = dsr<4096>(dsB_);   bHi[0][1] = dsr<5120>(dsB_); \
  bHi[1][0] = dsr<6144>(dsB_);   bHi[1][1] = dsr<7168>(dsB_); \
  ST_A(tA_, 0, (BUF_), vA_); \
  BAR(); WAIT_LGKM0(); \
  __builtin_amdgcn_s_setprio(1); \
  MF(0, 2, aLo, bHi); \
  __builtin_amdgcn_s_setprio(0); \
  BAR(); \
  /* ---- phase 4: Q11 (m4-7, n2-3) ---- */ \
  ST_A(tA_, 1, (BUF_), vA_); \
  asm volatile("s_waitcnt vmcnt(4)" ::: "memory"); \
  BAR(); \
  __builtin_amdgcn_s_setprio(1); \
  MF(4, 2, aHi, bHi); \
  __builtin_amdgcn_s_setprio(0); \
  BAR(); \
} while (0)

__global__ __launch_bounds__(512, 2) void MXFP4_gemm_kernel(
    const unsigned short* __restrict__ A,
    const unsigned short* __restrict__ B,
    const float* __restrict__ bias,
    float* __restrict__ C) {
  __shared__ unsigned short LDS[66560];  // 130 KB
  lds_us* lp = (lds_us*)LDS;

  const int tid  = threadIdx.x;
  const int lane = tid & 63;
  const int wv   = tid >> 6;   // wave 0..7
  const int wm   = wv >> 2;    // 0..1  (M half)
  const int wn   = wv & 3;     // 0..3  (N quarter)
  const int tid8 = tid * 8;

  // 2-D chunk XCD swizzle: XCD x owns an 8tm x 8tn sub-square (bijective).
  // Per-XCD L2 footprint: A 16 MB + B 16 MB (vs 64+4 for column-major).
  const int bid = blockIdx.x;
  const int xcd = bid & 7;
  const int idx = bid >> 3;                 // 0..63 within XCD
  const int tm  = (xcd & 3) * 8 + (idx & 7);   // 0..31
  const int tn  = (xcd >> 2) * 8 + (idx >> 3); // 0..15
  const int brow = tm * 256;
  const int bcol = tn * 256;

  // blocked-layout staging bases (identity copy: 16-KB block per (tile, half))
  const unsigned short* Abase = A + (size_t)(tm * 2) * 8192;
  const unsigned short* Bbase = B + (size_t)(tn * 2) * 8192;

  f32x4 acc[8][4] = {};
  bf16x8 aLo[4][2], aHi[4][2], bLo[2][2], bHi[2][2];

  // ---- prologue: tile 0 (A lo/hi, B lo/hi) + tile 1 A halves ----
  ST_A(0, 0, 0, true); ST_A(0, 1, 0, true);
  ST_B(0, 0, 0, true); ST_B(0, 1, 0, true);
  ST_A(1, 0, 1, true); ST_A(1, 1, 1, true);
  asm volatile("s_waitcnt vmcnt(4)" ::: "memory");  // tile 0 landed; A(1) in flight
  BAR();

  // ---- main loop: 31 iters x 2 K-tiles ----
  for (int it = 0; it < 31; ++it) {
    const int g0 = 2 * it;
    GROUP(0, g0 + 1, g0 + 2, true, true);
    GROUP(1, g0 + 2, g0 + 3, true, true);
  }
  // ---- tail groups 62, 63 (dummy stages keep vmcnt accounting uniform) ----
  GROUP(0, 63, 64, true, false);
  GROUP(1, 64, 65, false, false);

  // ---- epilogue: C = acc + bias;  frag: col=lane&15, row=(lane>>4)*4+j ----
  const int rb = brow + wm * 128 + (lane >> 4) * 4;
  const int cb = bcol + wn * 64 + (lane & 15);
#pragma unroll
  for (int n = 0; n < 4; ++n) {
    const int col = cb + n * 16;
    const float bv = bias[col];
#pragma unroll
    for (int m = 0; m < 8; ++m) {
      const int row = rb + m * 16;
#pragma unroll
      for (int j = 0; j < 4; ++j)
        C[(size_t)(row + j) * N_DIM + col] = acc[m][n][j] + bv;
    }
  }
}

extern "C" void kernel_launch(void* const* d_in, const int* in_sizes, int n_in,
                              void* d_out, int out_size, void* d_ws, size_t ws_size,
                              hipStream_t stream) {
  const float* x      = (const float*)d_in[0];
  const int*   wq     = (const int*)d_in[1];
  const float* scales = (const float*)d_in[2];
  const float* bias   = (const float*)d_in[3];
  float*       out    = (float*)d_out;

  unsigned short* wb = (unsigned short*)d_ws;                    // 33.5 MB blocked
  unsigned short* xb = wb + (size_t)N_DIM * K_DIM;               // 67 MB blocked

  MXFP4_dequant_kernel<<<(N_DIM * (long)K_DIM / 8) / 256, 256, 0, stream>>>(wq, scales, wb);
  MXFP4_cvt_kernel<<<(M_DIM * (long)K_DIM / 8) / 256, 256, 0, stream>>>(x, xb);

  MXFP4_gemm_kernel<<<512, 512, 0, stream>>>(xb, wb, bias, out);
}